// Round 7
// baseline (351.279 us; speedup 1.0000x reference)
//
#include <hip/hip_runtime.h>
#include <math.h>

#define NB   16
#define NN   16384
#define LDIM 512
#define DDIM 128
#define HIDD 128
#define NCLS 3
#define KCAP 256
#define CCAP 1024
#define ROWB 8
#define EPSV 1e-8f
#define DELTA 0.02f

typedef float  f32x4  __attribute__((ext_vector_type(4)));
typedef int    i32x4  __attribute__((ext_vector_type(4)));
typedef __bf16 bf16x8 __attribute__((ext_vector_type(8)));
typedef unsigned long long u64;

__device__ __forceinline__ int get_k(const int* kp) {
    int k = kp[0];
    if (k < 1 || k > NN) {
        float f = __int_as_float(k);
        if (f >= 1.0f && f <= (float)NN) k = (int)f;
        else k = 70;
    }
    if (k > NN) k = NN;
    return k;
}

__device__ __forceinline__ unsigned okey(float f) {
    unsigned u = __float_as_uint(f);
    return (u & 0x80000000u) ? ~u : (u | 0x80000000u);
}
__device__ __forceinline__ float inv_okey(unsigned k) {
    unsigned u = (k & 0x80000000u) ? (k & 0x7FFFFFFFu) : ~k;
    return __uint_as_float(u);
}

// pack two fp32 -> two RNE bf16 in one u32 (a -> low, b -> high)  [r2/r3-proven]
__device__ __forceinline__ unsigned pk2bf(float a, float b) {
    unsigned ua = __float_as_uint(a); ua = (ua + 0x7FFFu + ((ua >> 16) & 1u)) >> 16;
    unsigned ub = __float_as_uint(b); ub = (ub + 0x7FFFu + ((ub >> 16) & 1u)) & 0xFFFF0000u;
    return (ua & 0xFFFFu) | ub;
}

__device__ __forceinline__ f32x4 mfma16(i32x4 a, i32x4 b, f32x4 c) {
    return __builtin_amdgcn_mfma_f32_16x16x32_bf16(
        __builtin_bit_cast(bf16x8, a), __builtin_bit_cast(bf16x8, b), c, 0, 0, 0);
}

// async global->LDS, 16B per lane; LDS dest = wave-uniform base + lane*16
__device__ __forceinline__ void gl16(const void* g, void* l) {
    __builtin_amdgcn_global_load_lds(
        (const __attribute__((address_space(1))) void*)g,
        (__attribute__((address_space(3))) void*)l, 16, 0, 0);
}

__device__ __forceinline__ float sig_fast(float v)  { return 1.0f / (1.0f + __expf(-v)); }
__device__ __forceinline__ float tanh_fast(float v) { return 1.0f - 2.0f / (1.0f + __expf(2.0f * v)); }

// ---------------------------------------------------------------------------
// K0: swizzle Wv,Wu (fp32 [512][128]) into bf16 FRAGMENT-LANE order (r2-proven):
// short-idx = kt*8192 + g*4096 + nt*512 + lg*128 + lr*8 + j
// ---------------------------------------------------------------------------
__global__ void k0_prep(const float* __restrict__ Wv, const float* __restrict__ Wu,
                        unsigned short* __restrict__ Wp)
{
    int i = blockIdx.x * 256 + threadIdx.x;    // 0 .. 131071
    int g   = i >> 16;
    int rem = i & 65535;                       // kd*128 + n
    int kd  = rem >> 7;
    int n   = rem & 127;
    float w = g ? Wu[rem] : Wv[rem];
    unsigned u = __float_as_uint(w);
    u = (u + 0x7FFFu + ((u >> 16) & 1u)) >> 16;
    int kt = kd >> 5, lg = (kd >> 3) & 3, j = kd & 7, nt = n >> 4, lr = n & 15;
    Wp[kt * 8192 + g * 4096 + nt * 512 + lg * 128 + lr * 8 + j] = (unsigned short)u;
}

// ---------------------------------------------------------------------------
// K1: fused gated-attention logits, bf16 MFMA, async gload_lds 2-phase pipeline.
// Block 256 thr = 4 waves, BM=128 rows. Wave wid: gate g=wid&1, row-half
// h=wid>>1 -> 64 rows x 128 cols x 1 gate, acc[4][8] f32x4 = 128 VGPR.
// LDS 64KB: X fp32 dbuf 2x16KB (linear dest; source-side XOR chunk swizzle
// c^(row&7)) | B bf16 dbuf 2x16KB (frag-ordered Wp slice, linear).
// Per K-step: STAGE(next) via 8 gload_lds -> ds_read frags + cvt_pk + 32 MFMA
// -> one __syncthreads (its vmcnt(0) drain is covered by the compute phase).
// Epilogue: U-acc waves store to LDS, V-acc waves combine + shfl-reduce.
// ---------------------------------------------------------------------------
__global__ __launch_bounds__(256, 2)
void k1_mfma(const float* __restrict__ x, const unsigned short* __restrict__ Wp,
             const float* __restrict__ bv, const float* __restrict__ bu,
             const float* __restrict__ Wa, const float* __restrict__ ba,
             float* __restrict__ logits)
{
    __shared__ __align__(16) char lds[65536];  // X0 X1 (16KB ea) | B0 B1 (16KB ea)

    const int t   = threadIdx.x;
    const int wid = t >> 6;        // 0..3
    const int l   = t & 63;
    const int lr  = l & 15;
    const int lg  = l >> 4;
    const int g   = wid & 1;       // gate: 0=V, 1=U
    const int h   = wid >> 1;      // row half: rows [h*64, h*64+64)
    const int row0 = blockIdx.x * 128;

    f32x4 acc[4][8];
#pragma unroll
    for (int m = 0; m < 4; ++m)
#pragma unroll
        for (int nt = 0; nt < 8; ++nt)
            acc[m][nt] = f32x4{0.f, 0.f, 0.f, 0.f};

    // ---- staging addresses (x: per-lane source pre-swizzled, LDS linear) ----
    // instr xIdx=wid*4+j covers rows xIdx*8+(l>>3); lane slot s=l&7 holds
    // global chunk s^(l>>3)  (row&7 == l>>3 since xIdx*8 is 8-aligned)
    const int srow_sub = l >> 3;
    const int schunk   = (l & 7) ^ srow_sub;
    const float* xsrc[4];
#pragma unroll
    for (int j = 0; j < 4; ++j)
        xsrc[j] = x + (size_t)(row0 + (wid * 4 + j) * 8 + srow_sub) * LDIM + schunk * 4;
    const unsigned short* bsrc = Wp + (wid * 4) * 512 + l * 8;   // +j*512, +kt*8192

    // ---- frag read offsets ----
    // A (fp32): row R=h*64+m*16+lr; logical chunks 2lg,2lg+1; phys = c^(R&7)
    const int sx7 = lr & 7;
    int aoff0[4], aoff1[4];
#pragma unroll
    for (int m = 0; m < 4; ++m) {
        int R = h * 64 + m * 16 + lr;
        aoff0[m] = R * 128 + (((2 * lg    ) ^ sx7) * 16);
        aoff1[m] = R * 128 + (((2 * lg + 1) ^ sx7) * 16);
    }
    const int boff = g * 8192 + l * 16;   // + nt*1024

    // ---- prologue: stage kt=0 into buf 0 ----
#pragma unroll
    for (int j = 0; j < 4; ++j) {
        gl16(xsrc[j], lds + (wid * 4 + j) * 1024);
        gl16(bsrc + j * 512, lds + 32768 + (wid * 4 + j) * 1024);
    }
    __syncthreads();

#pragma unroll 2
    for (int kt = 0; kt < 16; ++kt) {
        const int p = kt & 1;
        // (1) issue next tile's async stages into the other buffer
        if (kt < 15) {
            const int np = p ^ 1;
#pragma unroll
            for (int j = 0; j < 4; ++j) {
                gl16(xsrc[j] + (size_t)(kt + 1) * 32,
                     lds + np * 16384 + (wid * 4 + j) * 1024);
                gl16(bsrc + (size_t)(kt + 1) * 8192 + j * 512,
                     lds + 32768 + np * 16384 + (wid * 4 + j) * 1024);
            }
        }
        // (2) frags from buf p + MFMA
        const char* Xb = lds + p * 16384;
        const char* Bb = lds + 32768 + p * 16384;
        i32x4 bf[8];
#pragma unroll
        for (int nt = 0; nt < 8; ++nt)
            bf[nt] = *(const i32x4*)(Bb + boff + nt * 1024);
#pragma unroll
        for (int m = 0; m < 4; ++m) {
            f32x4 c0 = *(const f32x4*)(Xb + aoff0[m]);
            f32x4 c1 = *(const f32x4*)(Xb + aoff1[m]);
            i32x4 a;
            a.x = pk2bf(c0.x, c0.y); a.y = pk2bf(c0.z, c0.w);
            a.z = pk2bf(c1.x, c1.y); a.w = pk2bf(c1.z, c1.w);
#pragma unroll
            for (int nt = 0; nt < 8; ++nt)
                acc[m][nt] = mfma16(a, bf[nt], acc[m][nt]);
        }
        // (3) one barrier: drains this step's stages (covered by (2)) and
        // protects buf p from being overwritten by kt+2's stage.
        __syncthreads();
    }

    // ---- epilogue: pair V (g=0) with U (g=1) across waves ----
    if (g == 1) {
        char* dst = lds + h * 32768;
#pragma unroll
        for (int m = 0; m < 4; ++m)
#pragma unroll
            for (int nt = 0; nt < 8; ++nt)
                *(f32x4*)(dst + ((m * 8 + nt) * 64 + l) * 16) = acc[m][nt];
    }
    __syncthreads();
    if (g == 0) {
        float bvc[8], buc[8], wac[8];
#pragma unroll
        for (int nt = 0; nt < 8; ++nt) {
            int col = nt * 16 + lr;
            bvc[nt] = bv[col]; buc[nt] = bu[col]; wac[nt] = Wa[col];
        }
        const float ba0 = ba[0];
        const char* src = lds + h * 32768;
#pragma unroll
        for (int m = 0; m < 4; ++m) {
            f32x4 ssum = f32x4{0.f, 0.f, 0.f, 0.f};
#pragma unroll
            for (int nt = 0; nt < 8; ++nt) {
                f32x4 u = *(const f32x4*)(src + ((m * 8 + nt) * 64 + l) * 16);
#pragma unroll
                for (int ri = 0; ri < 4; ++ri) {
                    float vv = tanh_fast(acc[m][nt][ri] + bvc[nt]);
                    float uu = sig_fast (u[ri]          + buc[nt]);
                    ssum[ri] = fmaf(vv * uu, wac[nt], ssum[ri]);
                }
            }
#pragma unroll
            for (int ri = 0; ri < 4; ++ri) {
                float s = ssum[ri];
                s += __shfl_xor(s, 1); s += __shfl_xor(s, 2);
                s += __shfl_xor(s, 4); s += __shfl_xor(s, 8);
                if (lr == 0)
                    logits[row0 + h * 64 + m * 16 + lg * 4 + ri] = s + ba0;
            }
        }
    }
}

// ---------------------------------------------------------------------------
// K3a: fused band-classify + softmax (verbatim r3/r6, verified).
// ---------------------------------------------------------------------------
__global__ void k3a_band_softmax(float* __restrict__ A, const float* __restrict__ mask,
                                 const int* __restrict__ kp, int* __restrict__ idxWS,
                                 int* __restrict__ candIdx, int* __restrict__ counts)
{
    __shared__ float sredf[4];
    __shared__ int sredi[4];
    __shared__ int sIn, sCand;
    const int b = blockIdx.x;
    const int t = threadIdx.x;
    const int w = t >> 6;
    int k = get_k(kp); if (k > KCAP) k = KCAP;
    float* Ab = A + (size_t)b * NN;
    const float* mb = mask + (size_t)b * NN;

    float raw[64]; u64 mbits = 0ULL;
#pragma unroll
    for (int j = 0; j < 64; ++j) {
        int i = t + j * 256;
        raw[j] = Ab[i];
        if (mb[i] > 0.0f) mbits |= (1ULL << j);
    }
    unsigned kk[64];
#pragma unroll
    for (int j = 0; j < 64; ++j) {
        float v = ((mbits >> j) & 1) ? raw[j] : -3.0e38f;
        kk[j] = okey(v);
    }
    unsigned lo = 0u, hi = 0xFFFFFFFFu;
    while (lo < hi) {
        unsigned span = hi - lo;
        unsigned mid = lo + (span >> 1) + (span & 1u);
        int c = 0;
#pragma unroll
        for (int j = 0; j < 64; ++j) c += (kk[j] >= mid) ? 1 : 0;
#pragma unroll
        for (int m2 = 1; m2 < 64; m2 <<= 1) c += __shfl_xor(c, m2);
        __syncthreads();
        if ((t & 63) == 0) sredi[w] = c;
        __syncthreads();
        c = sredi[0] + sredi[1] + sredi[2] + sredi[3];
        if (c >= k) lo = mid; else hi = mid - 1;
    }
    const float tv = inv_okey(lo);

    if (t == 0) { sIn = 0; sCand = 0; }
    __syncthreads();
    const float hiB = tv + DELTA, loB = tv - DELTA;
#pragma unroll
    for (int j = 0; j < 64; ++j) {
        int i = t + j * 256;
        float v = ((mbits >> j) & 1) ? raw[j] : -3.0e38f;
        if (v > hiB)       { int p = atomicAdd(&sIn, 1);   if (p < KCAP) idxWS[b * KCAP + p] = i; }
        else if (v >= loB) { int p = atomicAdd(&sCand, 1); if (p < CCAP) candIdx[b * CCAP + p] = i; }
    }

    float mx = -INFINITY;
#pragma unroll
    for (int j = 0; j < 64; ++j) mx = fmaxf(mx, raw[j]);
#pragma unroll
    for (int m2 = 1; m2 < 64; m2 <<= 1) mx = fmaxf(mx, __shfl_xor(mx, m2));
    __syncthreads();
    if ((t & 63) == 0) sredf[w] = mx;
    __syncthreads();
    mx = fmaxf(fmaxf(sredf[0], sredf[1]), fmaxf(sredf[2], sredf[3]));

    float sAll = 0.f, sM = 0.f;
#pragma unroll
    for (int j = 0; j < 64; ++j) {
        float e = __expf(raw[j] - mx);
        sAll += e;
        if ((mbits >> j) & 1) sM += e;
    }
#pragma unroll
    for (int m2 = 1; m2 < 64; m2 <<= 1) sAll += __shfl_xor(sAll, m2);
    __syncthreads();
    if ((t & 63) == 0) sredf[w] = sAll;
    __syncthreads();
    sAll = sredf[0] + sredf[1] + sredf[2] + sredf[3];
#pragma unroll
    for (int m2 = 1; m2 < 64; m2 <<= 1) sM += __shfl_xor(sM, m2);
    __syncthreads();
    if ((t & 63) == 0) sredf[w] = sM;
    __syncthreads();
    sM = sredf[0] + sredf[1] + sredf[2] + sredf[3];

    const float inv = 1.0f / (sM + EPSV * sAll);
#pragma unroll
    for (int j = 0; j < 64; ++j) {
        int i = t + j * 256;
        float e = __expf(raw[j] - mx);
        Ab[i] = ((mbits >> j) & 1) ? e * inv : 0.0f;
    }
    if (t == 0) {
        int m1 = sIn;   if (m1 > k)    m1 = k;
        int cc = sCand; if (cc > CCAP) cc = CCAP;
        counts[b * 4]     = m1;
        counts[b * 4 + 1] = cc;
    }
}

// ---------------------------------------------------------------------------
// K3b: exact fp32 logits for band candidates, row-batched (verbatim r6).
// ---------------------------------------------------------------------------
__global__ void k3b_exact(const float* __restrict__ x,
                          const float* __restrict__ Wv, const float* __restrict__ bv,
                          const float* __restrict__ Wu, const float* __restrict__ bu,
                          const float* __restrict__ Wa, const float* __restrict__ ba,
                          const int* __restrict__ candIdx, const int* __restrict__ counts,
                          float* __restrict__ candVal)
{
    __shared__ __align__(16) float sx[ROWB][LDIM];   // 16 KB
    __shared__ float sred[2][ROWB];
    const int b = blockIdx.x;
    const int t = threadIdx.x;          // 0..127  (thread t owns d-column t)
    const int w = t >> 6;
    const int cnt = counts[b * 4 + 1];
    const float bvt = bv[t], but = bu[t], wat = Wa[t], ba0 = ba[0];

    for (int base = blockIdx.y * ROWB; base < cnt; base += gridDim.y * ROWB) {
        const int nr = min(ROWB, cnt - base);
        for (int r = 0; r < nr; ++r) {
            const int row = candIdx[b * CCAP + base + r];
            ((f32x4*)&sx[r][0])[t] =
                ((const f32x4*)(x + ((size_t)b * NN + (size_t)row) * LDIM))[t];
        }
        __syncthreads();

        float dv[ROWB], du[ROWB];
#pragma unroll
        for (int r = 0; r < ROWB; ++r) { dv[r] = bvt; du[r] = but; }
#pragma unroll 4
        for (int ll = 0; ll < LDIM; ++ll) {
            const float wvl = Wv[ll * DDIM + t];
            const float wul = Wu[ll * DDIM + t];
#pragma unroll
            for (int r = 0; r < ROWB; ++r) {
                const float xv = sx[r][ll];   // LDS broadcast (uniform addr)
                dv[r] = fmaf(xv, wvl, dv[r]);
                du[r] = fmaf(xv, wul, du[r]);
            }
        }
#pragma unroll
        for (int r = 0; r < ROWB; ++r) {
            float c = tanhf(dv[r]) * (1.0f / (1.0f + expf(-du[r]))) * wat;
            c += __shfl_xor(c, 1);  c += __shfl_xor(c, 2);
            c += __shfl_xor(c, 4);  c += __shfl_xor(c, 8);
            c += __shfl_xor(c, 16); c += __shfl_xor(c, 32);
            if ((t & 63) == 0) sred[w][r] = c;
        }
        __syncthreads();
        if (t < nr) candVal[b * CCAP + base + t] = sred[0][t] + sred[1][t] + ba0;
        __syncthreads();
    }
}

// ---------------------------------------------------------------------------
// K34: select + rank-sort + gather + mean-pool + MLP + argmax (verbatim r3/r6).
// ---------------------------------------------------------------------------
__global__ void k34_select_final(const float* __restrict__ x, const int* __restrict__ kp,
                                 const int* __restrict__ candIdx, const float* __restrict__ candVal,
                                 const int* __restrict__ counts, const int* __restrict__ idxWS,
                                 const float* __restrict__ W1, const float* __restrict__ b1,
                                 const float* __restrict__ W2, const float* __restrict__ b2,
                                 float* __restrict__ Yprob, float* __restrict__ Yhat)
{
    __shared__ u64 keys[CCAP];
    __shared__ int sIdx[KCAP];
    __shared__ int sFinal[KCAP];
    __shared__ int sPos;
    __shared__ float sPooled[LDIM];
    __shared__ float sH[HIDD];
    __shared__ float sY[4];
    const int b = blockIdx.x;
    const int t = threadIdx.x;
    int k = get_k(kp); if (k > KCAP) k = KCAP;
    const int m1  = counts[b * 4];
    const int cnt = counts[b * 4 + 1];
    int need = k - m1; if (need < 0) need = 0; if (need > cnt) need = cnt;

    for (int i = t; i < cnt; i += 256)
        keys[i] = (((u64)okey(candVal[b * CCAP + i])) << 14)
                | (u64)(16383 - candIdx[b * CCAP + i]);
    if (t < m1) sIdx[t] = idxWS[b * KCAP + t];
    if (t == 0) sPos = 0;
    if (t < KCAP) sFinal[t] = 0;
    __syncthreads();
    for (int i = t; i < cnt; i += 256) {
        u64 mk = keys[i];
        int rank = 0;
        for (int j = 0; j < cnt; ++j) rank += (keys[j] > mk) ? 1 : 0;
        if (rank < need) { int p = atomicAdd(&sPos, 1); sIdx[m1 + p] = candIdx[b * CCAP + i]; }
    }
    __syncthreads();
    int tot = m1 + need; if (tot > k) tot = k;
    if (t < tot) {
        int myv = sIdx[t];
        int rank = 0;
        for (int e = 0; e < tot; ++e) rank += (sIdx[e] < myv) ? 1 : 0;
        sFinal[rank] = myv;
    }
    __syncthreads();

    float a0 = 0.0f, a1 = 0.0f;
    for (int j = 0; j < k; ++j) {
        const float* xr = x + ((size_t)b * NN + (size_t)sFinal[j]) * LDIM;
        a0 += xr[t];
        a1 += xr[t + 256];
    }
    const float invk = 1.0f / (float)k;
    sPooled[t]       = a0 * invk;
    sPooled[t + 256] = a1 * invk;
    __syncthreads();

    if (t < HIDD) {
        float acc = b1[t];
        for (int ll = 0; ll < LDIM; ++ll) acc = fmaf(sPooled[ll], W1[ll * HIDD + t], acc);
        sH[t] = fmaxf(acc, 0.0f);
    }
    __syncthreads();
    if (t < NCLS) {
        float y = b2[t];
        for (int hh = 0; hh < HIDD; ++hh) y = fmaf(sH[hh], W2[hh * NCLS + t], y);
        Yprob[b * NCLS + t] = y;
        sY[t] = y;
    }
    __syncthreads();
    if (t == 0) {
        int am = 0; float bst = sY[0];
        if (sY[1] > bst) { bst = sY[1]; am = 1; }
        if (sY[2] > bst) { bst = sY[2]; am = 2; }
        Yhat[b] = (float)am;
    }
}

// ---------------------------------------------------------------------------
extern "C" void kernel_launch(void* const* d_in, const int* in_sizes, int n_in,
                              void* d_out, int out_size, void* d_ws, size_t ws_size,
                              hipStream_t stream)
{
    const float* x    = (const float*)d_in[0];
    const float* mask = (const float*)d_in[1];
    const float* Wv   = (const float*)d_in[2];
    const float* bv   = (const float*)d_in[3];
    const float* Wu   = (const float*)d_in[4];
    const float* bu   = (const float*)d_in[5];
    const float* Wa   = (const float*)d_in[6];
    const float* ba   = (const float*)d_in[7];
    const float* W1   = (const float*)d_in[8];
    const float* b1   = (const float*)d_in[9];
    const float* W2   = (const float*)d_in[10];
    const float* b2   = (const float*)d_in[11];
    const int*   kp   = (const int*)d_in[12];

    float* out   = (float*)d_out;
    float* Yprob = out;        // [16,3] = 48
    float* Yhat  = out + 48;   // [16]
    float* A     = out + 64;   // [16,16384]  (logits first, softmax in-place)

    char* wsb = (char*)d_ws;
    unsigned short* Wp = (unsigned short*)wsb;        // 262144 B
    int*   idxWS   = (int*)  (wsb + 262144);          // 16 KB
    int*   candIdx = (int*)  (wsb + 278528);          // 64 KB
    float* candVal = (float*)(wsb + 344064);          // 64 KB
    int*   counts  = (int*)  (wsb + 409600);          // 256 B

    k0_prep  <<<512, 256, 0, stream>>>(Wv, Wu, Wp);
    k1_mfma  <<<2048, 256, 0, stream>>>(x, Wp, bv, bu, Wa, ba, A);
    k3a_band_softmax<<<NB, 256, 0, stream>>>(A, mask, kp, idxWS, candIdx, counts);
    k3b_exact<<<dim3(NB, 32), 128, 0, stream>>>(x, Wv, bv, Wu, bu, Wa, ba,
                                                candIdx, counts, candVal);
    k34_select_final<<<NB, 256, 0, stream>>>(x, kp, candIdx, candVal, counts, idxWS,
                                             W1, b1, W2, b2, Yprob, Yhat);
}

// Round 8
// 335.885 us; speedup vs baseline: 1.0458x; 1.0458x over previous
//
#include <hip/hip_runtime.h>
#include <math.h>

#define NB   16
#define NN   16384
#define LDIM 512
#define DDIM 128
#define HIDD 128
#define NCLS 3
#define KCAP 256
#define CCAP 1024
#define ROWB 8
#define EPSV 1e-8f
#define DELTA 0.02f

typedef float  f32x4  __attribute__((ext_vector_type(4)));
typedef int    i32x4  __attribute__((ext_vector_type(4)));
typedef unsigned u32x2 __attribute__((ext_vector_type(2)));
typedef __bf16 bf16x8 __attribute__((ext_vector_type(8)));
typedef unsigned long long u64;

__device__ __forceinline__ int get_k(const int* kp) {
    int k = kp[0];
    if (k < 1 || k > NN) {
        float f = __int_as_float(k);
        if (f >= 1.0f && f <= (float)NN) k = (int)f;
        else k = 70;
    }
    if (k > NN) k = NN;
    return k;
}

__device__ __forceinline__ unsigned okey(float f) {
    unsigned u = __float_as_uint(f);
    return (u & 0x80000000u) ? ~u : (u | 0x80000000u);
}
__device__ __forceinline__ float inv_okey(unsigned k) {
    unsigned u = (k & 0x80000000u) ? (k & 0x7FFFFFFFu) : ~k;
    return __uint_as_float(u);
}

// pack two fp32 -> two RNE bf16 in one u32 (a -> low, b -> high)  [r2/r3-proven]
__device__ __forceinline__ unsigned pk2bf(float a, float b) {
    unsigned ua = __float_as_uint(a); ua = (ua + 0x7FFFu + ((ua >> 16) & 1u)) >> 16;
    unsigned ub = __float_as_uint(b); ub = (ub + 0x7FFFu + ((ub >> 16) & 1u)) & 0xFFFF0000u;
    return (ua & 0xFFFFu) | ub;
}

__device__ __forceinline__ f32x4 mfma16(i32x4 a, i32x4 b, f32x4 c) {
    return __builtin_amdgcn_mfma_f32_16x16x32_bf16(
        __builtin_bit_cast(bf16x8, a), __builtin_bit_cast(bf16x8, b), c, 0, 0, 0);
}

__device__ __forceinline__ float sig_fast(float v)  { return 1.0f / (1.0f + __expf(-v)); }
__device__ __forceinline__ float tanh_fast(float v) { return 1.0f - 2.0f / (1.0f + __expf(2.0f * v)); }

// ---------------------------------------------------------------------------
// K0: swizzle Wv,Wu (fp32 [512][128]) into bf16 FRAGMENT-LANE order (r2-proven):
// short-idx = kt*8192 + g*4096 + nt*512 + lg*128 + lr*8 + j
// ---------------------------------------------------------------------------
__global__ void k0_prep(const float* __restrict__ Wv, const float* __restrict__ Wu,
                        unsigned short* __restrict__ Wp)
{
    int i = blockIdx.x * 256 + threadIdx.x;    // 0 .. 131071
    int g   = i >> 16;
    int rem = i & 65535;                       // kd*128 + n
    int kd  = rem >> 7;
    int n   = rem & 127;
    float w = g ? Wu[rem] : Wv[rem];
    unsigned u = __float_as_uint(w);
    u = (u + 0x7FFFu + ((u >> 16) & 1u)) >> 16;
    int kt = kd >> 5, lg = (kd >> 3) & 3, j = kd & 7, nt = n >> 4, lr = n & 15;
    Wp[kt * 8192 + g * 4096 + nt * 512 + lg * 128 + lr * 8 + j] = (unsigned short)u;
}

// ---------------------------------------------------------------------------
// K1 (v8): fused gated-attention logits; barrier-free MFMA mainloop.
// Grid = 256 blocks (1/CU) x 512 thr (8 waves). Wave wid owns d-cols
// [wid*16, wid*16+16) x both gates, ALL K in registers: Wreg[2][16] = 128 VGPR,
// preloaded ONCE per block. Block processes 32 tiles of 32 rows x K=512.
// LDS: x bf16 dbuf 2 x 32KB (full-K tile, row-XOR chunk swizzle) + sEp 1KB.
// Per tile: issue 8 global loads (tile j+1) -> 16 kt x {2 ds_read + 4 MFMA},
// NO barriers -> pack+write buf^1 -> epilogue reduce -> 2 barriers.
// ---------------------------------------------------------------------------
__global__ __launch_bounds__(512, 1)
void k1_mfma(const float* __restrict__ x, const unsigned short* __restrict__ Wp,
             const float* __restrict__ bv, const float* __restrict__ bu,
             const float* __restrict__ Wa, const float* __restrict__ ba,
             float* __restrict__ logits)
{
    __shared__ __align__(16) char lds[66560];  // buf0 32K | buf1 32K | sEp 1K

    const int t   = threadIdx.x;   // 0..511
    const int wid = t >> 6;        // 0..7
    const int l   = t & 63;
    const int lr  = l & 15;
    const int lg  = l >> 4;
    const int l7  = lr & 7;

    // ---- wave-resident weights: frag (g, nt=wid, kt) at lane l ----
    i32x4 Wreg[2][16];
    {
        const unsigned short* wb = Wp + wid * 512 + l * 8;
#pragma unroll
        for (int kt = 0; kt < 16; ++kt) {
#pragma unroll
            for (int g = 0; g < 2; ++g)
                Wreg[g][kt] = *(const i32x4*)(wb + kt * 8192 + g * 4096);
        }
    }

    // epilogue constants (this wave's 16 cols)
    const int d = wid * 16 + lr;
    const float bvd = bv[d], bud = bu[d], wad = Wa[d];
    const float ba0 = ba[0];

    // staging role: thread t handles 16B-chunk c=t&127 of rows r0, r0+4, ...
    const int c     = t & 127;
    const int r0    = t >> 7;        // 0..3
    const int chalf = c & 1;
    const int clog  = c >> 1;        // 0..63 (16B chunk within row)

    const size_t blk_row0 = (size_t)blockIdx.x * 1024;
    const float* xblk = x + blk_row0 * LDIM;
    float* sEp = (float*)(lds + 65536);   // [8 waves][32 rows]

    f32x4 acc[2][2];
    f32x4 xg[8];

    // ---- prologue: stage tile 0 into buf0 ----
#pragma unroll
    for (int i = 0; i < 8; ++i)
        xg[i] = *(const f32x4*)(xblk + (size_t)(i * 4 + r0) * LDIM + c * 4);
#pragma unroll
    for (int i = 0; i < 8; ++i) {
        int row = i * 4 + r0;
        u32x2 wv; wv.x = pk2bf(xg[i].x, xg[i].y); wv.y = pk2bf(xg[i].z, xg[i].w);
        *(u32x2*)(lds + row * 1024 + ((clog ^ (row & 7)) * 16) + chalf * 8) = wv;
    }
    __syncthreads();

    int p = 0;
    for (int j = 0; j < 32; ++j) {
        const bool has_next = (j < 31);
        // (1) issue tile j+1 global loads (latency hides under mainloop)
        if (has_next) {
            const float* xt = xblk + (size_t)(j + 1) * 32 * LDIM;
#pragma unroll
            for (int i = 0; i < 8; ++i)
                xg[i] = *(const f32x4*)(xt + (size_t)(i * 4 + r0) * LDIM + c * 4);
        }
        // (2) barrier-free mainloop over full K
#pragma unroll
        for (int g = 0; g < 2; ++g)
#pragma unroll
            for (int rt = 0; rt < 2; ++rt)
                acc[g][rt] = f32x4{0.f, 0.f, 0.f, 0.f};
        const char* Xb = lds + p * 32768;
#pragma unroll
        for (int kt = 0; kt < 16; ++kt) {
            i32x4 a0 = *(const i32x4*)(Xb + lr * 1024        + (((kt * 4 + lg) ^ l7) * 16));
            i32x4 a1 = *(const i32x4*)(Xb + (16 + lr) * 1024 + (((kt * 4 + lg) ^ l7) * 16));
            acc[0][0] = mfma16(a0, Wreg[0][kt], acc[0][0]);
            acc[1][0] = mfma16(a0, Wreg[1][kt], acc[1][0]);
            acc[0][1] = mfma16(a1, Wreg[0][kt], acc[0][1]);
            acc[1][1] = mfma16(a1, Wreg[1][kt], acc[1][1]);
        }
        // (3) pack + write tile j+1 into the other buffer (no conflict: that
        // buffer was last read two tiles ago, separated by two barriers)
        if (has_next) {
            char* Xw = lds + (p ^ 1) * 32768;
#pragma unroll
            for (int i = 0; i < 8; ++i) {
                int row = i * 4 + r0;
                u32x2 wv; wv.x = pk2bf(xg[i].x, xg[i].y); wv.y = pk2bf(xg[i].z, xg[i].w);
                *(u32x2*)(Xw + row * 1024 + ((clog ^ (row & 7)) * 16) + chalf * 8) = wv;
            }
        }
        // (4) epilogue: gate combine + reduce over this wave's 16 cols
#pragma unroll
        for (int rt = 0; rt < 2; ++rt) {
#pragma unroll
            for (int ri = 0; ri < 4; ++ri) {
                float vv = tanh_fast(acc[0][rt][ri] + bvd);
                float uu = sig_fast (acc[1][rt][ri] + bud);
                float s  = vv * uu * wad;
                s += __shfl_xor(s, 1); s += __shfl_xor(s, 2);
                s += __shfl_xor(s, 4); s += __shfl_xor(s, 8);
                if (lr == 0) sEp[wid * 32 + rt * 16 + lg * 4 + ri] = s;
            }
        }
        __syncthreads();
        if (t < 32) {
            float s = ba0;
#pragma unroll
            for (int w2 = 0; w2 < 8; ++w2) s += sEp[w2 * 32 + t];
            logits[blk_row0 + j * 32 + t] = s;
        }
        __syncthreads();   // protects sEp reuse + publishes buf p^1
        p ^= 1;
    }
}

// ---------------------------------------------------------------------------
// K3a: fused band-classify + softmax (verbatim r3/r6, verified).
// ---------------------------------------------------------------------------
__global__ void k3a_band_softmax(float* __restrict__ A, const float* __restrict__ mask,
                                 const int* __restrict__ kp, int* __restrict__ idxWS,
                                 int* __restrict__ candIdx, int* __restrict__ counts)
{
    __shared__ float sredf[4];
    __shared__ int sredi[4];
    __shared__ int sIn, sCand;
    const int b = blockIdx.x;
    const int t = threadIdx.x;
    const int w = t >> 6;
    int k = get_k(kp); if (k > KCAP) k = KCAP;
    float* Ab = A + (size_t)b * NN;
    const float* mb = mask + (size_t)b * NN;

    float raw[64]; u64 mbits = 0ULL;
#pragma unroll
    for (int j = 0; j < 64; ++j) {
        int i = t + j * 256;
        raw[j] = Ab[i];
        if (mb[i] > 0.0f) mbits |= (1ULL << j);
    }
    unsigned kk[64];
#pragma unroll
    for (int j = 0; j < 64; ++j) {
        float v = ((mbits >> j) & 1) ? raw[j] : -3.0e38f;
        kk[j] = okey(v);
    }
    unsigned lo = 0u, hi = 0xFFFFFFFFu;
    while (lo < hi) {
        unsigned span = hi - lo;
        unsigned mid = lo + (span >> 1) + (span & 1u);
        int c = 0;
#pragma unroll
        for (int j = 0; j < 64; ++j) c += (kk[j] >= mid) ? 1 : 0;
#pragma unroll
        for (int m2 = 1; m2 < 64; m2 <<= 1) c += __shfl_xor(c, m2);
        __syncthreads();
        if ((t & 63) == 0) sredi[w] = c;
        __syncthreads();
        c = sredi[0] + sredi[1] + sredi[2] + sredi[3];
        if (c >= k) lo = mid; else hi = mid - 1;
    }
    const float tv = inv_okey(lo);

    if (t == 0) { sIn = 0; sCand = 0; }
    __syncthreads();
    const float hiB = tv + DELTA, loB = tv - DELTA;
#pragma unroll
    for (int j = 0; j < 64; ++j) {
        int i = t + j * 256;
        float v = ((mbits >> j) & 1) ? raw[j] : -3.0e38f;
        if (v > hiB)       { int p = atomicAdd(&sIn, 1);   if (p < KCAP) idxWS[b * KCAP + p] = i; }
        else if (v >= loB) { int p = atomicAdd(&sCand, 1); if (p < CCAP) candIdx[b * CCAP + p] = i; }
    }

    float mx = -INFINITY;
#pragma unroll
    for (int j = 0; j < 64; ++j) mx = fmaxf(mx, raw[j]);
#pragma unroll
    for (int m2 = 1; m2 < 64; m2 <<= 1) mx = fmaxf(mx, __shfl_xor(mx, m2));
    __syncthreads();
    if ((t & 63) == 0) sredf[w] = mx;
    __syncthreads();
    mx = fmaxf(fmaxf(sredf[0], sredf[1]), fmaxf(sredf[2], sredf[3]));

    float sAll = 0.f, sM = 0.f;
#pragma unroll
    for (int j = 0; j < 64; ++j) {
        float e = __expf(raw[j] - mx);
        sAll += e;
        if ((mbits >> j) & 1) sM += e;
    }
#pragma unroll
    for (int m2 = 1; m2 < 64; m2 <<= 1) sAll += __shfl_xor(sAll, m2);
    __syncthreads();
    if ((t & 63) == 0) sredf[w] = sAll;
    __syncthreads();
    sAll = sredf[0] + sredf[1] + sredf[2] + sredf[3];
#pragma unroll
    for (int m2 = 1; m2 < 64; m2 <<= 1) sM += __shfl_xor(sM, m2);
    __syncthreads();
    if ((t & 63) == 0) sredf[w] = sM;
    __syncthreads();
    sM = sredf[0] + sredf[1] + sredf[2] + sredf[3];

    const float inv = 1.0f / (sM + EPSV * sAll);
#pragma unroll
    for (int j = 0; j < 64; ++j) {
        int i = t + j * 256;
        float e = __expf(raw[j] - mx);
        Ab[i] = ((mbits >> j) & 1) ? e * inv : 0.0f;
    }
    if (t == 0) {
        int m1 = sIn;   if (m1 > k)    m1 = k;
        int cc = sCand; if (cc > CCAP) cc = CCAP;
        counts[b * 4]     = m1;
        counts[b * 4 + 1] = cc;
    }
}

// ---------------------------------------------------------------------------
// K3b: exact fp32 logits for band candidates, row-batched (verbatim r6/r7).
// ---------------------------------------------------------------------------
__global__ void k3b_exact(const float* __restrict__ x,
                          const float* __restrict__ Wv, const float* __restrict__ bv,
                          const float* __restrict__ Wu, const float* __restrict__ bu,
                          const float* __restrict__ Wa, const float* __restrict__ ba,
                          const int* __restrict__ candIdx, const int* __restrict__ counts,
                          float* __restrict__ candVal)
{
    __shared__ __align__(16) float sx[ROWB][LDIM];   // 16 KB
    __shared__ float sred[2][ROWB];
    const int b = blockIdx.x;
    const int t = threadIdx.x;          // 0..127  (thread t owns d-column t)
    const int w = t >> 6;
    const int cnt = counts[b * 4 + 1];
    const float bvt = bv[t], but = bu[t], wat = Wa[t], ba0 = ba[0];

    for (int base = blockIdx.y * ROWB; base < cnt; base += gridDim.y * ROWB) {
        const int nr = min(ROWB, cnt - base);
        for (int r = 0; r < nr; ++r) {
            const int row = candIdx[b * CCAP + base + r];
            ((f32x4*)&sx[r][0])[t] =
                ((const f32x4*)(x + ((size_t)b * NN + (size_t)row) * LDIM))[t];
        }
        __syncthreads();

        float dv[ROWB], du[ROWB];
#pragma unroll
        for (int r = 0; r < ROWB; ++r) { dv[r] = bvt; du[r] = but; }
#pragma unroll 4
        for (int ll = 0; ll < LDIM; ++ll) {
            const float wvl = Wv[ll * DDIM + t];
            const float wul = Wu[ll * DDIM + t];
#pragma unroll
            for (int r = 0; r < ROWB; ++r) {
                const float xv = sx[r][ll];   // LDS broadcast (uniform addr)
                dv[r] = fmaf(xv, wvl, dv[r]);
                du[r] = fmaf(xv, wul, du[r]);
            }
        }
#pragma unroll
        for (int r = 0; r < ROWB; ++r) {
            float c = tanhf(dv[r]) * (1.0f / (1.0f + expf(-du[r]))) * wat;
            c += __shfl_xor(c, 1);  c += __shfl_xor(c, 2);
            c += __shfl_xor(c, 4);  c += __shfl_xor(c, 8);
            c += __shfl_xor(c, 16); c += __shfl_xor(c, 32);
            if ((t & 63) == 0) sred[w][r] = c;
        }
        __syncthreads();
        if (t < nr) candVal[b * CCAP + base + t] = sred[0][t] + sred[1][t] + ba0;
        __syncthreads();
    }
}

// ---------------------------------------------------------------------------
// K34: select + rank-sort + gather + mean-pool + MLP + argmax (verbatim r3+).
// ---------------------------------------------------------------------------
__global__ void k34_select_final(const float* __restrict__ x, const int* __restrict__ kp,
                                 const int* __restrict__ candIdx, const float* __restrict__ candVal,
                                 const int* __restrict__ counts, const int* __restrict__ idxWS,
                                 const float* __restrict__ W1, const float* __restrict__ b1,
                                 const float* __restrict__ W2, const float* __restrict__ b2,
                                 float* __restrict__ Yprob, float* __restrict__ Yhat)
{
    __shared__ u64 keys[CCAP];
    __shared__ int sIdx[KCAP];
    __shared__ int sFinal[KCAP];
    __shared__ int sPos;
    __shared__ float sPooled[LDIM];
    __shared__ float sH[HIDD];
    __shared__ float sY[4];
    const int b = blockIdx.x;
    const int t = threadIdx.x;
    int k = get_k(kp); if (k > KCAP) k = KCAP;
    const int m1  = counts[b * 4];
    const int cnt = counts[b * 4 + 1];
    int need = k - m1; if (need < 0) need = 0; if (need > cnt) need = cnt;

    for (int i = t; i < cnt; i += 256)
        keys[i] = (((u64)okey(candVal[b * CCAP + i])) << 14)
                | (u64)(16383 - candIdx[b * CCAP + i]);
    if (t < m1) sIdx[t] = idxWS[b * KCAP + t];
    if (t == 0) sPos = 0;
    if (t < KCAP) sFinal[t] = 0;
    __syncthreads();
    for (int i = t; i < cnt; i += 256) {
        u64 mk = keys[i];
        int rank = 0;
        for (int j = 0; j < cnt; ++j) rank += (keys[j] > mk) ? 1 : 0;
        if (rank < need) { int p = atomicAdd(&sPos, 1); sIdx[m1 + p] = candIdx[b * CCAP + i]; }
    }
    __syncthreads();
    int tot = m1 + need; if (tot > k) tot = k;
    if (t < tot) {
        int myv = sIdx[t];
        int rank = 0;
        for (int e = 0; e < tot; ++e) rank += (sIdx[e] < myv) ? 1 : 0;
        sFinal[rank] = myv;
    }
    __syncthreads();

    float a0 = 0.0f, a1 = 0.0f;
    for (int j = 0; j < k; ++j) {
        const float* xr = x + ((size_t)b * NN + (size_t)sFinal[j]) * LDIM;
        a0 += xr[t];
        a1 += xr[t + 256];
    }
    const float invk = 1.0f / (float)k;
    sPooled[t]       = a0 * invk;
    sPooled[t + 256] = a1 * invk;
    __syncthreads();

    if (t < HIDD) {
        float acc = b1[t];
        for (int ll = 0; ll < LDIM; ++ll) acc = fmaf(sPooled[ll], W1[ll * HIDD + t], acc);
        sH[t] = fmaxf(acc, 0.0f);
    }
    __syncthreads();
    if (t < NCLS) {
        float y = b2[t];
        for (int hh = 0; hh < HIDD; ++hh) y = fmaf(sH[hh], W2[hh * NCLS + t], y);
        Yprob[b * NCLS + t] = y;
        sY[t] = y;
    }
    __syncthreads();
    if (t == 0) {
        int am = 0; float bst = sY[0];
        if (sY[1] > bst) { bst = sY[1]; am = 1; }
        if (sY[2] > bst) { bst = sY[2]; am = 2; }
        Yhat[b] = (float)am;
    }
}

// ---------------------------------------------------------------------------
extern "C" void kernel_launch(void* const* d_in, const int* in_sizes, int n_in,
                              void* d_out, int out_size, void* d_ws, size_t ws_size,
                              hipStream_t stream)
{
    const float* x    = (const float*)d_in[0];
    const float* mask = (const float*)d_in[1];
    const float* Wv   = (const float*)d_in[2];
    const float* bv   = (const float*)d_in[3];
    const float* Wu   = (const float*)d_in[4];
    const float* bu   = (const float*)d_in[5];
    const float* Wa   = (const float*)d_in[6];
    const float* ba   = (const float*)d_in[7];
    const float* W1   = (const float*)d_in[8];
    const float* b1   = (const float*)d_in[9];
    const float* W2   = (const float*)d_in[10];
    const float* b2   = (const float*)d_in[11];
    const int*   kp   = (const int*)d_in[12];

    float* out   = (float*)d_out;
    float* Yprob = out;        // [16,3] = 48
    float* Yhat  = out + 48;   // [16]
    float* A     = out + 64;   // [16,16384]  (logits first, softmax in-place)

    char* wsb = (char*)d_ws;
    unsigned short* Wp = (unsigned short*)wsb;        // 262144 B
    int*   idxWS   = (int*)  (wsb + 262144);          // 16 KB
    int*   candIdx = (int*)  (wsb + 278528);          // 64 KB
    float* candVal = (float*)(wsb + 344064);          // 64 KB
    int*   counts  = (int*)  (wsb + 409600);          // 256 B

    k0_prep  <<<512, 256, 0, stream>>>(Wv, Wu, Wp);
    k1_mfma  <<<256, 512, 0, stream>>>(x, Wp, bv, bu, Wa, ba, A);
    k3a_band_softmax<<<NB, 256, 0, stream>>>(A, mask, kp, idxWS, candIdx, counts);
    k3b_exact<<<dim3(NB, 32), 128, 0, stream>>>(x, Wv, bv, Wu, bu, Wa, ba,
                                                candIdx, counts, candVal);
    k34_select_final<<<NB, 256, 0, stream>>>(x, kp, candIdx, candVal, counts, idxWS,
                                             W1, b1, W2, b2, Yprob, Yhat);
}